// Round 1
// baseline (590.201 us; speedup 1.0000x reference)
//
#include <hip/hip_runtime.h>
#include <hip/hip_bf16.h>

// LQLinear: out = x @ quantize(weight, basis)^T + bias
// M=8192 tokens, N=4096 out_features, K=4096 in_features.
// Q_T=1 and new_basis is discarded => the LSQ refit does NOT affect output.

#define M_TOK 8192
#define N_OUT 4096
#define K_IN  4096

typedef __attribute__((ext_vector_type(8))) short short8;   // 8 bf16 (4 VGPRs)
typedef __attribute__((ext_vector_type(4))) float floatx4;  // MFMA C/D frag

typedef __attribute__((address_space(1))) const void gvoid_t;
typedef __attribute__((address_space(3))) void lvoid_t;

// round-to-nearest-even fp32 -> bf16 (bit trick; no NaN in this data)
__device__ __forceinline__ ushort f2bf(float f) {
    unsigned u = __float_as_uint(f);
    u += 0x7fffu + ((u >> 16) & 1u);
    return (ushort)(u >> 16);
}

// ---------------- fused prep: x fp32->bf16  +  weight quantize ----------------
// Grid-stride with capped grid (G11): one-elem-per-thread with 32k blocks ran at
// ~1.3 TB/s; loop per thread + 3072 total blocks targets ~6 TB/s streaming.
// Block-uniform branch: blocks [0,2048) convert X, [2048,3072) quantize W
// (2:1 split matches the 201MB:100MB traffic ratio).
#define PREP_XBLK 2048
#define PREP_WBLK 1024

__global__ __launch_bounds__(256) void prep(
        const float4* __restrict__ x,  short8* __restrict__ xb,
        const float4* __restrict__ w,  const float* __restrict__ basis,
        short8* __restrict__ wqo) {
    if (blockIdx.x < PREP_XBLK) {
        const int tid    = blockIdx.x * 256 + threadIdx.x;
        const int stride = PREP_XBLK * 256;
        const int n8     = (M_TOK * K_IN) / 8;          // 4194304 -> 8 iters/thread
        for (int i = tid; i < n8; i += stride) {
            float4 a = x[2 * i], b = x[2 * i + 1];      // 32B/lane read
            short8 o;
            o[0] = (short)f2bf(a.x); o[1] = (short)f2bf(a.y);
            o[2] = (short)f2bf(a.z); o[3] = (short)f2bf(a.w);
            o[4] = (short)f2bf(b.x); o[5] = (short)f2bf(b.y);
            o[6] = (short)f2bf(b.z); o[7] = (short)f2bf(b.w);
            xb[i] = o;                                  // 16B/lane write
        }
    } else {
        float b0 = basis[0], b1 = basis[1];
        // levels = encodings({-1,+1}^2) @ [b0,b1], sorted ascending (network)
        float l0 = -b0 - b1, l1 = -b0 + b1, l2 = b0 - b1, l3 = b0 + b1;
        float t;
        if (l0 > l1) { t = l0; l0 = l1; l1 = t; }
        if (l2 > l3) { t = l2; l2 = l3; l3 = t; }
        if (l0 > l2) { t = l0; l0 = l2; l2 = t; }
        if (l1 > l3) { t = l1; l1 = l3; l3 = t; }
        if (l1 > l2) { t = l1; l1 = l2; l2 = t; }
        // midpoint thresholds; searchsorted 'left' => idx = #{thres < w}
        const float t0 = 0.5f * (l0 + l1), t1 = 0.5f * (l1 + l2), t2 = 0.5f * (l2 + l3);
        const int tid    = (blockIdx.x - PREP_XBLK) * 256 + threadIdx.x;
        const int stride = PREP_WBLK * 256;
        const int n8     = (N_OUT * K_IN) / 8;          // 2097152 -> 8 iters/thread
#define QF(vv) ((vv > t1) ? ((vv > t2) ? l3 : l2) : ((vv > t0) ? l1 : l0))
        for (int i = tid; i < n8; i += stride) {
            float4 a = w[2 * i], b = w[2 * i + 1];
            short8 o;
            o[0] = (short)f2bf(QF(a.x)); o[1] = (short)f2bf(QF(a.y));
            o[2] = (short)f2bf(QF(a.z)); o[3] = (short)f2bf(QF(a.w));
            o[4] = (short)f2bf(QF(b.x)); o[5] = (short)f2bf(QF(b.y));
            o[6] = (short)f2bf(QF(b.z)); o[7] = (short)f2bf(QF(b.w));
            wqo[i] = o;
        }
#undef QF
    }
}

// ---------------- GEMM: C[M][N] = A[M][K] * B[N][K]^T + bias ----------------
// m97 structure: 128x128 block tile, BK=64, 4 waves in 2x2, each wave 4x4
// tiles of 16x16x32 MFMA. global_load_lds width=16 staging.
// LDS XOR swizzle at 16B-chunk granularity: physical chunk c of row r holds
// global chunk (c ^ (r&7)). Breaks the 128B-row-stride 16-way bank conflict
// (all quad lanes previously hit one 4-bank group) down to free 2-way.
__global__ __launch_bounds__(256) void gemm_bt(
        const ushort* __restrict__ A,   // bf16 [M][K]
        const ushort* __restrict__ B,   // bf16 [N][K]
        const float* __restrict__ bias, // [N]
        float* __restrict__ C) {        // fp32 [M][N]
    __shared__ ushort As[128 * 64];
    __shared__ ushort Bs[128 * 64];

    const int lane = threadIdx.x & 63;
    const int wv   = threadIdx.x >> 6;      // 0..3
    const int bm0  = blockIdx.y * 128;
    const int bn0  = blockIdx.x * 128;
    const int wm   = (wv >> 1) * 64;        // wave row offset in block tile
    const int wn   = (wv & 1) * 64;         // wave col offset

    floatx4 acc[4][4] = {};

    // staging: per wave 4 instrs for A, 4 for B; each instr = 8 rows x 64 cols
    const int lr = lane >> 3;               // 0..7  (row within 8-row group)
    const int lc = lane & 7;                // 0..7  (16B chunk within row)
    // XOR swizzle: this lane's LDS slot (row lr, chunk lc) must receive
    // global chunk (lc ^ lr) of row lr.
    const ushort* ag = A + (size_t)(bm0 + wv * 32 + lr) * K_IN + (lc ^ lr) * 8;
    const ushort* bg = B + (size_t)(bn0 + wv * 32 + lr) * K_IN + (lc ^ lr) * 8;
    ushort* asl = As + (wv * 32) * 64;      // wave-uniform LDS base
    ushort* bsl = Bs + (wv * 32) * 64;

    // MFMA fragment addressing (16x16x32): lane holds row lane&15, k quad*8..+7
    const int mrow = lane & 15;
    const int quad = lane >> 4;             // 0..3
    // physical chunk for ks: ((quad | ks*4) ^ (mrow&7)) == (quad^(mrow&7)) ^ ks*4
    const int cswz = (quad ^ (mrow & 7)) * 8;   // ushort offset, ks adds 32

    for (int kt = 0; kt < K_IN / 64; ++kt) {
#pragma unroll
        for (int t = 0; t < 4; ++t) {
            __builtin_amdgcn_global_load_lds((gvoid_t*)(ag + (size_t)t * 8 * K_IN),
                                             (lvoid_t*)(asl + t * 8 * 64), 16, 0, 0);
            __builtin_amdgcn_global_load_lds((gvoid_t*)(bg + (size_t)t * 8 * K_IN),
                                             (lvoid_t*)(bsl + t * 8 * 64), 16, 0, 0);
        }
        ag += 64; bg += 64;
        __syncthreads();
#pragma unroll
        for (int ks = 0; ks < 2; ++ks) {
            short8 af[4], bfv[4];
#pragma unroll
            for (int i = 0; i < 4; ++i)
                af[i] = *(const short8*)(As + (wm + i * 16 + mrow) * 64 + (cswz ^ (ks * 32)));
#pragma unroll
            for (int j = 0; j < 4; ++j)
                bfv[j] = *(const short8*)(Bs + (wn + j * 16 + mrow) * 64 + (cswz ^ (ks * 32)));
#pragma unroll
            for (int i = 0; i < 4; ++i)
#pragma unroll
                for (int j = 0; j < 4; ++j)
                    acc[i][j] = __builtin_amdgcn_mfma_f32_16x16x32_bf16(
                        af[i], bfv[j], acc[i][j], 0, 0, 0);
        }
        __syncthreads();
    }

    // epilogue: C/D layout col=lane&15, row=(lane>>4)*4+reg
    const int r0 = (lane >> 4) * 4;
    const int cc = lane & 15;
#pragma unroll
    for (int j = 0; j < 4; ++j) {
        const int col = bn0 + wn + j * 16 + cc;
        const float bj = bias[col];
#pragma unroll
        for (int i = 0; i < 4; ++i) {
#pragma unroll
            for (int r = 0; r < 4; ++r) {
                const int row = bm0 + wm + i * 16 + r0 + r;
                C[(size_t)row * N_OUT + col] = acc[i][j][r] + bj;
            }
        }
    }
}

extern "C" void kernel_launch(void* const* d_in, const int* in_sizes, int n_in,
                              void* d_out, int out_size, void* d_ws, size_t ws_size,
                              hipStream_t stream) {
    const float* x     = (const float*)d_in[0];  // [8192,4096]
    const float* w     = (const float*)d_in[1];  // [4096,4096]
    const float* bias  = (const float*)d_in[2];  // [4096]
    const float* basis = (const float*)d_in[3];  // [2]
    float* out = (float*)d_out;                  // [8192,4096] fp32

    ushort* Xb = (ushort*)d_ws;                      // 8192*4096 bf16 = 67.1 MB
    ushort* Wq = Xb + (size_t)M_TOK * K_IN;          // 4096*4096 bf16 = 33.5 MB

    prep<<<PREP_XBLK + PREP_WBLK, 256, 0, stream>>>(
        (const float4*)x, (short8*)Xb, (const float4*)w, basis, (short8*)Wq);

    {
        dim3 grid(N_OUT / 128, M_TOK / 128);         // (32, 64)
        gemm_bt<<<grid, 256, 0, stream>>>(Xb, Wq, bias, out);
    }
}

// Round 2
// 490.198 us; speedup vs baseline: 1.2040x; 1.2040x over previous
//
#include <hip/hip_runtime.h>
#include <hip/hip_bf16.h>

// LQLinear: out = x @ quantize(weight, basis)^T + bias
// M=8192 tokens, N=4096 out_features, K=4096 in_features.
// Q_T=1 and new_basis is discarded => the LSQ refit does NOT affect output.

#define M_TOK 8192
#define N_OUT 4096
#define K_IN  4096

typedef __attribute__((ext_vector_type(8))) short short8;   // 8 bf16 (4 VGPRs)
typedef __attribute__((ext_vector_type(4))) float floatx4;  // MFMA C/D frag

typedef __attribute__((address_space(1))) const void gvoid_t;
typedef __attribute__((address_space(3))) void lvoid_t;

// round-to-nearest-even fp32 -> bf16 (bit trick; no NaN in this data)
__device__ __forceinline__ ushort f2bf(float f) {
    unsigned u = __float_as_uint(f);
    u += 0x7fffu + ((u >> 16) & 1u);
    return (ushort)(u >> 16);
}

// ---------------- fused prep: x fp32->bf16  +  weight quantize ----------------
#define PREP_XBLK 2048
#define PREP_WBLK 1024

__global__ __launch_bounds__(256) void prep(
        const float4* __restrict__ x,  short8* __restrict__ xb,
        const float4* __restrict__ w,  const float* __restrict__ basis,
        short8* __restrict__ wqo) {
    if (blockIdx.x < PREP_XBLK) {
        const int tid    = blockIdx.x * 256 + threadIdx.x;
        const int stride = PREP_XBLK * 256;
        const int n8     = (M_TOK * K_IN) / 8;
        for (int i = tid; i < n8; i += stride) {
            float4 a = x[2 * i], b = x[2 * i + 1];
            short8 o;
            o[0] = (short)f2bf(a.x); o[1] = (short)f2bf(a.y);
            o[2] = (short)f2bf(a.z); o[3] = (short)f2bf(a.w);
            o[4] = (short)f2bf(b.x); o[5] = (short)f2bf(b.y);
            o[6] = (short)f2bf(b.z); o[7] = (short)f2bf(b.w);
            xb[i] = o;
        }
    } else {
        float b0 = basis[0], b1 = basis[1];
        float l0 = -b0 - b1, l1 = -b0 + b1, l2 = b0 - b1, l3 = b0 + b1;
        float t;
        if (l0 > l1) { t = l0; l0 = l1; l1 = t; }
        if (l2 > l3) { t = l2; l2 = l3; l3 = t; }
        if (l0 > l2) { t = l0; l0 = l2; l2 = t; }
        if (l1 > l3) { t = l1; l1 = l3; l3 = t; }
        if (l1 > l2) { t = l1; l1 = l2; l2 = t; }
        const float t0 = 0.5f * (l0 + l1), t1 = 0.5f * (l1 + l2), t2 = 0.5f * (l2 + l3);
        const int tid    = (blockIdx.x - PREP_XBLK) * 256 + threadIdx.x;
        const int stride = PREP_WBLK * 256;
        const int n8     = (N_OUT * K_IN) / 8;
#define QF(vv) ((vv > t1) ? ((vv > t2) ? l3 : l2) : ((vv > t0) ? l1 : l0))
        for (int i = tid; i < n8; i += stride) {
            float4 a = w[2 * i], b = w[2 * i + 1];
            short8 o;
            o[0] = (short)f2bf(QF(a.x)); o[1] = (short)f2bf(QF(a.y));
            o[2] = (short)f2bf(QF(a.z)); o[3] = (short)f2bf(QF(a.w));
            o[4] = (short)f2bf(QF(b.x)); o[5] = (short)f2bf(QF(b.y));
            o[6] = (short)f2bf(QF(b.z)); o[7] = (short)f2bf(QF(b.w));
            wqo[i] = o;
        }
#undef QF
    }
}

// ---------------- GEMM 256x256, BK=64, 8-phase counted-vmcnt schedule -------
// C[M][N] = A[M][K] * B[N][K]^T + bias.
// 512 threads = 8 waves (2 M x 4 N), per-wave output 128x64 (acc[8][4]).
// LDS 128KiB: As[2][256*64] + Bs[2][256*64] bf16, buffer parity = K-tile parity.
// Per iteration: 8 phases process 2 K-tiles; each phase = {ds_reads, stage 1
// half-tile (2 global_load_lds/wave), barrier, 16 MFMA (setprio), barrier}.
// Phase read plan [12,8,4,0]: B fully consumed after ph1, A after ph3 -> the
// per-phase stages into the CURRENTLY-READ buffer are read-safe:
//   ph1: (t+1).A1 | ph2: (t+2).B0 | ph3: (t+2).B1 | ph4: (t+2).A0 + vmcnt(6)
//   ph5: (t+2).A1 | ph6: (t+3).B0 | ph7: (t+3).B1 | ph8: (t+3).A0 + vmcnt(6)
// vmcnt(6) = 3 half-tiles (2 loads each) allowed in flight; at ph4 it proves
// (t+1).A1 (and all older = all of t+1) landed before ph5 reads buf1; at ph8
// it proves all of t+2 landed before next iteration's ph1 reads buf0.
// LDS XOR swizzle (verified, 0 conflicts): physical 16B chunk c of row r holds
// global chunk c^(r&7); staging pre-swizzles the GLOBAL source address so the
// linear global_load_lds destination stays contiguous.

#define NIT 32   // iterations; 2 K-tiles each; K = 64 tiles of BK=64

#define BAR() do { asm volatile("" ::: "memory"); \
                   __builtin_amdgcn_s_barrier(); \
                   asm volatile("" ::: "memory"); \
                   __builtin_amdgcn_sched_barrier(0); } while (0)
#define VMC6() asm volatile("s_waitcnt vmcnt(6)" ::: "memory")
#define VMC0() asm volatile("s_waitcnt vmcnt(0)" ::: "memory")

// stage half h (128 rows) of K-tile tt of A/B into its parity buffer.
// per wave: 2 instrs, each 8 rows x 64 cols (64 lanes x 16B).
#define STAGE_A(tt, h) do { const int _p = (tt) & 1;                          \
    __builtin_amdgcn_global_load_lds(                                         \
        (gvoid_t*)(ag + (size_t)((h) * 128) * K_IN + (tt) * 64),              \
        (lvoid_t*)(As + _p * 16384 + ((h) * 128 + wid * 16) * 64), 16, 0, 0); \
    __builtin_amdgcn_global_load_lds(                                         \
        (gvoid_t*)(ag + (size_t)((h) * 128 + 8) * K_IN + (tt) * 64),          \
        (lvoid_t*)(As + _p * 16384 + ((h) * 128 + wid * 16 + 8) * 64), 16, 0, 0); \
} while (0)
#define STAGE_B(tt, h) do { const int _p = (tt) & 1;                          \
    __builtin_amdgcn_global_load_lds(                                         \
        (gvoid_t*)(bg + (size_t)((h) * 128) * K_IN + (tt) * 64),              \
        (lvoid_t*)(Bs + _p * 16384 + ((h) * 128 + wid * 16) * 64), 16, 0, 0); \
    __builtin_amdgcn_global_load_lds(                                         \
        (gvoid_t*)(bg + (size_t)((h) * 128 + 8) * K_IN + (tt) * 64),          \
        (lvoid_t*)(Bs + _p * 16384 + ((h) * 128 + wid * 16 + 8) * 64), 16, 0, 0); \
} while (0)

#define MFMA_PAIR(MA, MB) do {                                                \
    __builtin_amdgcn_s_setprio(1);                                           \
    _Pragma("unroll") for (int nj = 0; nj < 4; ++nj) {                        \
        acc[MA][nj] = __builtin_amdgcn_mfma_f32_16x16x32_bf16(                \
            af[MA][0], bfv[nj][0], acc[MA][nj], 0, 0, 0);                     \
        acc[MA][nj] = __builtin_amdgcn_mfma_f32_16x16x32_bf16(                \
            af[MA][1], bfv[nj][1], acc[MA][nj], 0, 0, 0);                     \
    }                                                                         \
    _Pragma("unroll") for (int nj = 0; nj < 4; ++nj) {                        \
        acc[MB][nj] = __builtin_amdgcn_mfma_f32_16x16x32_bf16(                \
            af[MB][0], bfv[nj][0], acc[MB][nj], 0, 0, 0);                     \
        acc[MB][nj] = __builtin_amdgcn_mfma_f32_16x16x32_bf16(                \
            af[MB][1], bfv[nj][1], acc[MB][nj], 0, 0, 0);                     \
    }                                                                         \
    __builtin_amdgcn_s_setprio(0);                                            \
} while (0)

// one 4-phase group: read K-tile from buffer PB; stage A(TS1,h1) if C1 at ph1,
// B(TS2,h0/h1) at ph2/ph3, A(TS2,h0)+vmcnt at ph4 (all guarded by CM).
#define GROUP4(PB, TS1, C1, TS2, CM) do {                                     \
    const ushort* Ab = As + (PB) * 16384;                                     \
    const ushort* Bb = Bs + (PB) * 16384;                                     \
    short8 af[8][2], bfv[4][2];                                               \
    /* phase 1: read all B + A rows 0-31 (12 reads) */                        \
    _Pragma("unroll") for (int nj = 0; nj < 4; ++nj)                          \
        _Pragma("unroll") for (int ks = 0; ks < 2; ++ks)                      \
            bfv[nj][ks] = *(const short8*)(Bb + (wn + nj * 16 + mrow) * 64 + (cswz ^ (ks * 32))); \
    _Pragma("unroll") for (int mi = 0; mi < 2; ++mi)                          \
        _Pragma("unroll") for (int ks = 0; ks < 2; ++ks)                      \
            af[mi][ks] = *(const short8*)(Ab + (wm + mi * 16 + mrow) * 64 + (cswz ^ (ks * 32))); \
    if (C1) { STAGE_A(TS1, 1); }                                              \
    BAR();                                                                    \
    MFMA_PAIR(0, 1);                                                          \
    BAR();                                                                    \
    /* phase 2: read A rows 32-95 (8 reads) */                                \
    _Pragma("unroll") for (int mi = 2; mi < 6; ++mi)                          \
        _Pragma("unroll") for (int ks = 0; ks < 2; ++ks)                      \
            af[mi][ks] = *(const short8*)(Ab + (wm + mi * 16 + mrow) * 64 + (cswz ^ (ks * 32))); \
    if (CM) { STAGE_B(TS2, 0); }                                              \
    BAR();                                                                    \
    MFMA_PAIR(2, 3);                                                          \
    BAR();                                                                    \
    /* phase 3: read A rows 96-127 (4 reads) */                               \
    _Pragma("unroll") for (int mi = 6; mi < 8; ++mi)                          \
        _Pragma("unroll") for (int ks = 0; ks < 2; ++ks)                      \
            af[mi][ks] = *(const short8*)(Ab + (wm + mi * 16 + mrow) * 64 + (cswz ^ (ks * 32))); \
    if (CM) { STAGE_B(TS2, 1); }                                              \
    BAR();                                                                    \
    MFMA_PAIR(4, 5);                                                          \
    BAR();                                                                    \
    /* phase 4: no reads */                                                   \
    if (CM) { STAGE_A(TS2, 0); VMC6(); } else { VMC0(); }                     \
    BAR();                                                                    \
    MFMA_PAIR(6, 7);                                                          \
    BAR();                                                                    \
} while (0)

extern "C" __global__ __launch_bounds__(512, 2) void gemm256(
        const ushort* __restrict__ A,   // bf16 [M][K]
        const ushort* __restrict__ B,   // bf16 [N][K]
        const float* __restrict__ bias, // [N]
        float* __restrict__ C) {        // fp32 [M][N]
    extern __shared__ ushort smem[];    // 128 KiB
    ushort* As = smem;                  // [2][256*64]
    ushort* Bs = smem + 32768;          // [2][256*64]

    const int tid  = threadIdx.x;
    const int lane = tid & 63;
    const int wid  = tid >> 6;          // 0..7
    const int wr   = wid >> 2;          // 0..1
    const int wc   = wid & 3;           // 0..3
    const int wm   = wr * 128;          // wave row offset in 256 tile
    const int wn   = wc * 64;           // wave col offset

    // bijective XCD swizzle: 512 blocks, 512 % 8 == 0
    const int bid = blockIdx.x;
    const int swz = (bid & 7) * 64 + (bid >> 3);
    const int bn0 = (swz & 15) * 256;   // N/256 = 16
    const int bm0 = (swz >> 4) * 256;   // M/256 = 32

    // staging source (pre-swizzled global chunk = lc ^ lr)
    const int lr = lane >> 3, lc = lane & 7;
    const ushort* ag = A + (size_t)(bm0 + wid * 16 + lr) * K_IN + (lc ^ lr) * 8;
    const ushort* bg = B + (size_t)(bn0 + wid * 16 + lr) * K_IN + (lc ^ lr) * 8;

    // MFMA fragment addressing (16x16x32): lane = (quad, mrow)
    const int mrow = lane & 15;
    const int quad = lane >> 4;
    const int cswz = (quad ^ (mrow & 7)) * 8;   // ushort offset; ks XORs 32

    floatx4 acc[8][4] = {};

    // prologue: tile0 fully + tile1 {B0,B1,A0}; vmcnt(6) proves tile0 landed
    STAGE_B(0, 0); STAGE_B(0, 1); STAGE_A(0, 0); STAGE_A(0, 1);
    STAGE_B(1, 0); STAGE_B(1, 1); STAGE_A(1, 0);
    VMC6();
    BAR();

#pragma unroll 1
    for (int it = 0; it < NIT; ++it) {
        const bool more = (it + 1 < NIT);
        GROUP4(0, 2 * it + 1, true, 2 * it + 2, more);
        GROUP4(1, 2 * it + 2, more, 2 * it + 3, more);
    }

    // epilogue: C/D layout col=lane&15, row=(lane>>4)*4+reg
    const int r0 = (lane >> 4) * 4;
    const int cc = lane & 15;
#pragma unroll
    for (int nj = 0; nj < 4; ++nj) {
        const int col = bn0 + wn + nj * 16 + cc;
        const float bj = bias[col];
#pragma unroll
        for (int mi = 0; mi < 8; ++mi) {
#pragma unroll
            for (int r = 0; r < 4; ++r) {
                const int row = bm0 + wm + mi * 16 + r0 + r;
                C[(size_t)row * N_OUT + col] = acc[mi][nj][r] + bj;
            }
        }
    }
}

extern "C" void kernel_launch(void* const* d_in, const int* in_sizes, int n_in,
                              void* d_out, int out_size, void* d_ws, size_t ws_size,
                              hipStream_t stream) {
    const float* x     = (const float*)d_in[0];  // [8192,4096]
    const float* w     = (const float*)d_in[1];  // [4096,4096]
    const float* bias  = (const float*)d_in[2];  // [4096]
    const float* basis = (const float*)d_in[3];  // [2]
    float* out = (float*)d_out;                  // [8192,4096] fp32

    ushort* Xb = (ushort*)d_ws;                      // 8192*4096 bf16 = 67.1 MB
    ushort* Wq = Xb + (size_t)M_TOK * K_IN;          // 4096*4096 bf16 = 33.5 MB

    prep<<<PREP_XBLK + PREP_WBLK, 256, 0, stream>>>(
        (const float4*)x, (short8*)Xb, (const float4*)w, basis, (short8*)Wq);

    // 128 KiB dynamic LDS needs the attribute raised past the 64 KiB default
    (void)hipFuncSetAttribute((const void*)gemm256,
                              hipFuncAttributeMaxDynamicSharedMemorySize, 131072);
    gemm256<<<dim3(512), 512, 131072, stream>>>(Xb, Wq, bias, out);
}